// Round 1
// baseline (248.833 us; speedup 1.0000x reference)
//
#include <hip/hip_runtime.h>

// ---------------------------------------------------------------------------
// EnhancedBlockGabor on MI355X (gfx950)
// Pipeline:
//   prep_x     : x (fp32) -> 4 column-phase-shifted, zero-padded bf16 replicas
//   prep_small : filters -> A matrix bf16 [48][256] (kx,ky padded 15->16),
//                w1 -> bf16 [32 ch][32 o][32 so(pad)]
//   conv_mix   : implicit-GEMM depthwise conv (mfma 16x16x32 bf16) + |.| +
//                fused channel-mixing GEMM; writes fp32 y-partials (2 halves)
//   inorm      : sum halves, instance-norm per (b,o), H<->W transposed store
// b1 is ignored: a per-channel constant cancels under instance norm.
// ---------------------------------------------------------------------------

typedef __attribute__((ext_vector_type(8))) short bfx8;
typedef __attribute__((ext_vector_type(4))) short bfx4;
typedef __attribute__((ext_vector_type(4))) float fx4;

#define NREP   4
#define RPITCH 144
#define RROWS  144
#define IMG_SH (RROWS * RPITCH)        // 20736 shorts per padded image
#define REP_SH (128 * IMG_SH)          // shorts per replica (all 128 images)
#define XREP_SH (NREP * REP_SH)        // 10,616,832 shorts

#define A_OFF   ((size_t)XREP_SH * 2)              // bytes into ws
#define W1B_OFF (A_OFF + (size_t)48 * 256 * 2)
#define YP_OFF  (W1B_OFF + (size_t)32 * 32 * 32 * 2)
#define YP_HALF (4 * 32 * 16384)                   // floats per c-half partial
// total ws need: YP_OFF + 2*YP_HALF*4 = 38,100,992 B (~36.3 MiB)

__device__ __forceinline__ unsigned short f2bf(float f) {
    unsigned u = __float_as_uint(f);
    u = (u + 0x7FFFu + ((u >> 16) & 1u)) >> 16;   // RTNE
    return (unsigned short)u;
}

// ---- x -> padded bf16 replicas: xrep[phi][img][r][p] = x_pad[img][r][p+phi]
__global__ void prep_x(const float* __restrict__ x, unsigned* __restrict__ xrep)
{
    const int DW_PER_ROW = RPITCH / 2;             // 72
    const int DW_PER_IMG = IMG_SH / 2;             // 10368
    const int DW_PER_REP = REP_SH / 2;             // 1,327,104
    const int total = NREP * DW_PER_REP;
    for (int i = blockIdx.x * blockDim.x + threadIdx.x; i < total;
         i += gridDim.x * blockDim.x) {
        int phi  = i / DW_PER_REP;
        int rem  = i - phi * DW_PER_REP;
        int img  = rem / DW_PER_IMG;
        int rem2 = rem - img * DW_PER_IMG;
        int r    = rem2 / DW_PER_ROW;
        int pd   = rem2 - r * DW_PER_ROW;
        int c0   = 2 * pd + phi;                   // absolute padded col of lo short
        float v0 = 0.f, v1 = 0.f;
        int rr = r - 7;
        if (rr >= 0 && rr < 128) {
            const float* row = x + ((size_t)img * 128 + rr) * 128;
            int cc0 = c0 - 7;
            if (cc0 >= 0 && cc0 < 128) v0 = row[cc0];
            int cc1 = c0 - 6;
            if (cc1 >= 0 && cc1 < 128) v1 = row[cc1];
        }
        xrep[i] = (unsigned)f2bf(v0) | ((unsigned)f2bf(v1) << 16);
    }
}

// ---- filters -> A[48][256] bf16 ; w1 -> w1b[32][32][32] bf16
__global__ void prep_small(const float* __restrict__ filt, const float* __restrict__ w1,
                           unsigned short* __restrict__ A, unsigned short* __restrict__ w1b)
{
    int t = blockIdx.x * blockDim.x + threadIdx.x;
    if (t < 48 * 256) {
        int f = t >> 8, k = t & 255;
        int ky = k >> 4, kx = k & 15;
        float v = 0.f;
        if (ky < 15 && kx < 15) v = filt[(f * 15 + ky) * 15 + kx];
        A[t] = f2bf(v);
    } else if (t < 48 * 256 + 32 * 32 * 32) {
        int j = t - 48 * 256;
        int c = j >> 10, o = (j >> 5) & 31, so = j & 31;
        float v = (so < 24) ? w1[o * 768 + c * 24 + so] : 0.f;
        w1b[j] = f2bf(v);
    }
}

// ---- fused conv + magnitude + channel-mix --------------------------------
// grid 1024: XCD-swizzled so each XCD owns one (b, c-half) -> 2.65 MB L2 set.
// WG = 256 thr = 4 waves; WG owns one output row h (128 px), loops 16 channels.
// Per wave: 2 n-tiles of 16 px. conv: M=48 (3 mt) x K=256 (8 s) ; mix: M=32.
__launch_bounds__(256, 2)
__global__ void conv_mix(const unsigned short* __restrict__ xrep,
                         const unsigned short* __restrict__ Aw,
                         const unsigned short* __restrict__ w1b,
                         float* __restrict__ ypart)
{
    __shared__ unsigned short mag_lds[4][32][32];  // [wave][px][so pad32]
    const int tid  = threadIdx.x;
    const int lane = tid & 63;
    const int wave = tid >> 6;
    const int n    = lane & 15;                    // MFMA row(A) / col(B,D)
    const int q    = lane >> 4;                    // MFMA k-octet / D row group

    const int bid  = blockIdx.x;
    const int swiz = (bid & 7) * 128 + (bid >> 3); // XCD k -> (b,half)=k, all h
    const int b    = swiz >> 8;
    const int half = (swiz >> 7) & 1;
    const int h    = swiz & 127;

    // zero so=24..31 pads once (w1b pads are 0 too, but 0*NaN protection)
    if (lane < 32) *(int4*)&mag_lds[wave][lane][24] = make_int4(0, 0, 0, 0);

    // A fragments (filters) pinned in VGPRs for the whole kernel: 96 VGPRs
    bfx8 af[3][8];
#pragma unroll
    for (int mt = 0; mt < 3; ++mt)
#pragma unroll
        for (int s = 0; s < 8; ++s)
            af[mt][s] = *(const bfx8*)(Aw + ((mt * 16 + n) * 256 + s * 32 + q * 8));

    const int px0   = wave * 32;
    const int phi   = n & 3;                           // replica phase
    const int pbase = px0 + (n & 12) + 8 * (q & 1);    // aligned col start
    const int rbase = h + (q >> 1);                    // + 2s per k-step
    const unsigned short* xb =
        xrep + ((size_t)(phi * 128 + b * 32 + half * 16) * RROWS + rbase) * RPITCH + pbase;

    const fx4 zero4 = {0.f, 0.f, 0.f, 0.f};
    fx4 yacc[2][2];
#pragma unroll
    for (int mt = 0; mt < 2; ++mt)
#pragma unroll
        for (int t = 0; t < 2; ++t) yacc[mt][t] = zero4;

    for (int c = 0; c < 16; ++c) {
        const unsigned short* xc = xb + c * IMG_SH;
        // stage all B data for this channel: 32 aligned 8B loads
        bfx4 braw[2][8][2];
#pragma unroll
        for (int s = 0; s < 8; ++s)
#pragma unroll
            for (int t = 0; t < 2; ++t) {
                const bfx4* p = (const bfx4*)(xc + s * (2 * RPITCH) + t * 16);
                braw[t][s][0] = p[0];
                braw[t][s][1] = p[1];
            }
        const int ch = half * 16 + c;
        bfx8 wf[2];
#pragma unroll
        for (int mt = 0; mt < 2; ++mt)
            wf[mt] = *(const bfx8*)(w1b + ((ch * 32 + mt * 16 + n) * 32 + q * 8));

        fx4 cacc[3][2];
#pragma unroll
        for (int mt = 0; mt < 3; ++mt)
#pragma unroll
            for (int t = 0; t < 2; ++t) cacc[mt][t] = zero4;

#pragma unroll
        for (int s = 0; s < 8; ++s) {
#pragma unroll
            for (int t = 0; t < 2; ++t) {
                bfx8 bf = __builtin_shufflevector(braw[t][s][0], braw[t][s][1],
                                                  0, 1, 2, 3, 4, 5, 6, 7);
#pragma unroll
                for (int mt = 0; mt < 3; ++mt)
                    cacc[mt][t] = __builtin_amdgcn_mfma_f32_16x16x32_bf16(
                        af[mt][s], bf, cacc[mt][t], 0, 0, 0);
            }
        }

        // magnitudes -> wave-private LDS (D rows 4q..4q+3 = re/im pairs)
#pragma unroll
        for (int t = 0; t < 2; ++t)
#pragma unroll
            for (int mt = 0; mt < 3; ++mt) {
                float m0 = sqrtf(cacc[mt][t][0] * cacc[mt][t][0] +
                                 cacc[mt][t][1] * cacc[mt][t][1]);
                float m1 = sqrtf(cacc[mt][t][2] * cacc[mt][t][2] +
                                 cacc[mt][t][3] * cacc[mt][t][3]);
                unsigned pk = (unsigned)f2bf(m0) | ((unsigned)f2bf(m1) << 16);
                *(unsigned*)&mag_lds[wave][t * 16 + n][8 * mt + 2 * q] = pk;
            }
        asm volatile("s_waitcnt lgkmcnt(0)" ::: "memory");

        // mix: y[o][px] += w1[o][so] * mag[so][px]
#pragma unroll
        for (int t = 0; t < 2; ++t) {
            bfx8 mb = *(const bfx8*)&mag_lds[wave][t * 16 + n][q * 8];
#pragma unroll
            for (int mt = 0; mt < 2; ++mt)
                yacc[mt][t] = __builtin_amdgcn_mfma_f32_16x16x32_bf16(
                    wf[mt], mb, yacc[mt][t], 0, 0, 0);
        }
    }

    // epilogue: y-partial for this c-half, fp32, [half][b][o][h][w]
    float* yp = ypart + (size_t)(half * 4 + b) * (32 * 16384) + h * 128;
#pragma unroll
    for (int mt = 0; mt < 2; ++mt)
#pragma unroll
        for (int t = 0; t < 2; ++t) {
            const int w0 = px0 + t * 16 + n;
#pragma unroll
            for (int r = 0; r < 4; ++r)
                yp[(size_t)(mt * 16 + 4 * q + r) * 16384 + w0] = yacc[mt][t][r];
        }
}

// ---- instance norm + transposed store ------------------------------------
__global__ void inorm(const float* __restrict__ ypart, float* __restrict__ out)
{
    const int bo = blockIdx.x;             // 128 = (b,o) pairs
    const int b = bo >> 5, o = bo & 31;
    const float* y0 = ypart + (size_t)(b * 32 + o) * 16384;
    const float* y1 = y0 + YP_HALF;
    const int tid = threadIdx.x;

    float s = 0.f, sq = 0.f;
    for (int i = tid; i < 16384; i += 256) {
        float v = y0[i] + y1[i];
        s += v; sq += v * v;
    }
    for (int off = 32; off > 0; off >>= 1) {
        s  += __shfl_down(s, off);
        sq += __shfl_down(sq, off);
    }
    __shared__ float rs[4], rq[4], mv[2];
    const int lane = tid & 63, wave = tid >> 6;
    if (lane == 0) { rs[wave] = s; rq[wave] = sq; }
    __syncthreads();
    if (tid == 0) {
        float S = rs[0] + rs[1] + rs[2] + rs[3];
        float Q = rq[0] + rq[1] + rq[2] + rq[3];
        float mean = S * (1.f / 16384.f);
        float var  = Q * (1.f / 16384.f) - mean * mean;
        var = fmaxf(var, 0.f);
        mv[0] = mean;
        mv[1] = rsqrtf(var + 1e-5f);
    }
    __syncthreads();
    const float mean = mv[0], rstd = mv[1];
    float* ob = out + (size_t)(b * 32 + o) * 16384;
    for (int i = tid; i < 16384; i += 256) {
        float v = (y0[i] + y1[i] - mean) * rstd;
        int hp = i >> 7, wp = i & 127;
        ob[wp * 128 + hp] = v;            // out[.., h=wp, w=hp] = z[hp, wp]
    }
}

extern "C" void kernel_launch(void* const* d_in, const int* in_sizes, int n_in,
                              void* d_out, int out_size, void* d_ws, size_t ws_size,
                              hipStream_t stream)
{
    const float* x    = (const float*)d_in[0];
    const float* filt = (const float*)d_in[1];
    const float* w1   = (const float*)d_in[2];
    // d_in[3] = b1: cancels under instance norm, unused.
    float* out = (float*)d_out;
    char* ws = (char*)d_ws;

    unsigned*       xrep = (unsigned*)ws;
    unsigned short* Aw   = (unsigned short*)(ws + A_OFF);
    unsigned short* w1b  = (unsigned short*)(ws + W1B_OFF);
    float*          yp   = (float*)(ws + YP_OFF);

    prep_x<<<2048, 256, 0, stream>>>(x, xrep);
    prep_small<<<176, 256, 0, stream>>>(filt, w1, Aw, w1b);
    conv_mix<<<1024, 256, 0, stream>>>((const unsigned short*)xrep, Aw, w1b, yp);
    inorm<<<128, 256, 0, stream>>>(yp, out);
}

// Round 2
// 225.417 us; speedup vs baseline: 1.1039x; 1.1039x over previous
//
#include <hip/hip_runtime.h>

// ---------------------------------------------------------------------------
// EnhancedBlockGabor on MI355X (gfx950)
//   prep_x     : x (fp32) -> 4 column-phase-shifted, zero-padded bf16 replicas
//   prep_small : filters -> A bf16 [48][256]; w1 -> bf16 [32][32][32]; zero stats
//   conv_mix   : implicit-GEMM depthwise conv (mfma 16x16x32 bf16) + |.| +
//                fused channel-mix GEMM; fp32 y-partials (2 c-halves)
//   istats     : sum/sumsq per (b,o) via block reduce + atomics
//   inorm2     : normalize + H<->W transpose via 32x32 LDS tiles
// b1 ignored: per-channel constant cancels under instance norm.
// R2 changes vs R1: removed asm memory clobber (was blocking A-fragment
// pinning -> 10.5 MB/CU L1 traffic), A pinned in 96 VGPRs, mag LDS padded
// 32->40 shorts (2-way=free), split/parallel instance norm with LDS-tile
// transpose (old version had 512B-stride uncoalesced stores).
// ---------------------------------------------------------------------------

typedef __attribute__((ext_vector_type(8))) short bfx8;
typedef __attribute__((ext_vector_type(4))) short bfx4;
typedef __attribute__((ext_vector_type(4))) float fx4;
typedef __attribute__((ext_vector_type(4))) unsigned ux4;

#define NREP   4
#define RPITCH 144
#define RROWS  144
#define IMG_SH (RROWS * RPITCH)        // 20736 shorts per padded image
#define REP_SH (128 * IMG_SH)          // shorts per replica (all 128 images)
#define XREP_SH (NREP * REP_SH)        // 10,616,832 shorts

#define A_OFF    ((size_t)XREP_SH * 2)             // bytes into ws
#define W1B_OFF  (A_OFF + (size_t)48 * 256 * 2)
#define YP_OFF   (W1B_OFF + (size_t)32 * 32 * 32 * 2)
#define YP_HALF  (4 * 32 * 16384)                  // floats per c-half partial
#define ST_OFF   (YP_OFF + (size_t)2 * YP_HALF * 4)
// total ws need: ST_OFF + 128*2*4 B  (~36.3 MiB)

#if __has_builtin(__builtin_amdgcn_sqrtf)
#define FSQRT __builtin_amdgcn_sqrtf
#else
#define FSQRT sqrtf
#endif

__device__ __forceinline__ unsigned short f2bf(float f) {
    unsigned u = __float_as_uint(f);
    u = (u + 0x7FFFu + ((u >> 16) & 1u)) >> 16;   // RTNE
    return (unsigned short)u;
}

// ---- x -> padded bf16 replicas: xrep[phi][img][r][p] = x_pad[img][r][p+phi]
__global__ void prep_x(const float* __restrict__ x, unsigned* __restrict__ xrep)
{
    const int DW_PER_ROW = RPITCH / 2;             // 72
    const int DW_PER_IMG = IMG_SH / 2;             // 10368
    const int DW_PER_REP = REP_SH / 2;             // 1,327,104
    const int total = NREP * DW_PER_REP;
    for (int i = blockIdx.x * blockDim.x + threadIdx.x; i < total;
         i += gridDim.x * blockDim.x) {
        int phi  = i / DW_PER_REP;
        int rem  = i - phi * DW_PER_REP;
        int img  = rem / DW_PER_IMG;
        int rem2 = rem - img * DW_PER_IMG;
        int r    = rem2 / DW_PER_ROW;
        int pd   = rem2 - r * DW_PER_ROW;
        int c0   = 2 * pd + phi;                   // absolute padded col of lo short
        float v0 = 0.f, v1 = 0.f;
        int rr = r - 7;
        if (rr >= 0 && rr < 128) {
            const float* row = x + ((size_t)img * 128 + rr) * 128;
            int cc0 = c0 - 7;
            if (cc0 >= 0 && cc0 < 128) v0 = row[cc0];
            int cc1 = c0 - 6;
            if (cc1 >= 0 && cc1 < 128) v1 = row[cc1];
        }
        xrep[i] = (unsigned)f2bf(v0) | ((unsigned)f2bf(v1) << 16);
    }
}

// ---- filters -> A[48][256] bf16 ; w1 -> w1b[32][32][32] bf16 ; zero stats
__global__ void prep_small(const float* __restrict__ filt, const float* __restrict__ w1,
                           unsigned short* __restrict__ A, unsigned short* __restrict__ w1b,
                           float* __restrict__ stats)
{
    int t = blockIdx.x * blockDim.x + threadIdx.x;
    if (t < 48 * 256) {
        int f = t >> 8, k = t & 255;
        int ky = k >> 4, kx = k & 15;
        float v = 0.f;
        if (ky < 15 && kx < 15) v = filt[(f * 15 + ky) * 15 + kx];
        A[t] = f2bf(v);
    } else if (t < 48 * 256 + 32 * 32 * 32) {
        int j = t - 48 * 256;
        int c = j >> 10, o = (j >> 5) & 31, so = j & 31;
        float v = (so < 24) ? w1[o * 768 + c * 24 + so] : 0.f;
        w1b[j] = f2bf(v);
    } else if (t < 48 * 256 + 32 * 32 * 32 + 256) {
        stats[t - (48 * 256 + 32 * 32 * 32)] = 0.f;
    }
}

// ---- fused conv + magnitude + channel-mix --------------------------------
// grid 1024, XCD-swizzled: each XCD owns one (b,c-half) -> 2.65 MB L2 set.
// WG = 256 thr = 4 waves, one output row h; 16 channels looped.
// A fragments (48x256 filters) pinned in 96 VGPRs -> ~230 VGPR, 2 blocks/CU.
__launch_bounds__(256, 2)
__global__ void conv_mix(const unsigned short* __restrict__ xrep,
                         const unsigned short* __restrict__ Aw,
                         const unsigned short* __restrict__ w1b,
                         float* __restrict__ ypart)
{
    __shared__ unsigned mag_lds[4][32][20];        // [wave][px][so-dword pad20]
    const int tid  = threadIdx.x;
    const int lane = tid & 63;
    const int wave = tid >> 6;
    const int n    = lane & 15;                    // MFMA row(A) / col(B,D)
    const int q    = lane >> 4;                    // MFMA k-octet / D row group

    const int bid  = blockIdx.x;
    const int swiz = (bid & 7) * 128 + (bid >> 3); // XCD k -> (b,half)=k, all h
    const int b    = swiz >> 8;
    const int half = (swiz >> 7) & 1;
    const int h    = swiz & 127;

    // zero so=24..31 pads once (dwords 12..15 of each px row)
    if (lane < 32) {
        ux4 z4 = {0u, 0u, 0u, 0u};
        *(ux4*)&mag_lds[wave][lane][12] = z4;
    }

    // A fragments (filters) pinned in VGPRs for the whole kernel: 96 VGPRs
    bfx8 af[3][8];
#pragma unroll
    for (int mt = 0; mt < 3; ++mt)
#pragma unroll
        for (int s = 0; s < 8; ++s)
            af[mt][s] = *(const bfx8*)(Aw + ((mt * 16 + n) * 256 + s * 32 + q * 8));

    const int px0   = wave * 32;
    const int phi   = n & 3;                           // replica phase
    const int pbase = px0 + (n & 12) + 8 * (q & 1);    // 8B-aligned col start
    const int rbase = h + (q >> 1);                    // + 2s per k-step
    const unsigned short* xb =
        xrep + ((size_t)(phi * 128 + b * 32 + half * 16) * RROWS + rbase) * RPITCH + pbase;

    const fx4 zero4 = {0.f, 0.f, 0.f, 0.f};
    fx4 yacc[2][2];
#pragma unroll
    for (int mt = 0; mt < 2; ++mt)
#pragma unroll
        for (int t = 0; t < 2; ++t) yacc[mt][t] = zero4;

    for (int c = 0; c < 16; ++c) {
        const unsigned short* xc = xb + c * IMG_SH;
        // stage all B data for this channel: 32 aligned 8B loads
        bfx4 braw[2][8][2];
#pragma unroll
        for (int s = 0; s < 8; ++s)
#pragma unroll
            for (int t = 0; t < 2; ++t) {
                const bfx4* p = (const bfx4*)(xc + s * (2 * RPITCH) + t * 16);
                braw[t][s][0] = p[0];
                braw[t][s][1] = p[1];
            }
        const int ch = half * 16 + c;
        bfx8 wf[2];
#pragma unroll
        for (int mt = 0; mt < 2; ++mt)
            wf[mt] = *(const bfx8*)(w1b + ((ch * 32 + mt * 16 + n) * 32 + q * 8));

        fx4 cacc[3][2];
#pragma unroll
        for (int mt = 0; mt < 3; ++mt)
#pragma unroll
            for (int t = 0; t < 2; ++t) cacc[mt][t] = zero4;

#pragma unroll
        for (int s = 0; s < 8; ++s) {
#pragma unroll
            for (int t = 0; t < 2; ++t) {
                bfx8 bf = __builtin_shufflevector(braw[t][s][0], braw[t][s][1],
                                                  0, 1, 2, 3, 4, 5, 6, 7);
#pragma unroll
                for (int mt = 0; mt < 3; ++mt)
                    cacc[mt][t] = __builtin_amdgcn_mfma_f32_16x16x32_bf16(
                        af[mt][s], bf, cacc[mt][t], 0, 0, 0);
            }
        }

        // magnitudes -> wave-private LDS (D rows 4q..4q+3 = two re/im pairs)
#pragma unroll
        for (int t = 0; t < 2; ++t)
#pragma unroll
            for (int mt = 0; mt < 3; ++mt) {
                float m0 = FSQRT(cacc[mt][t][0] * cacc[mt][t][0] +
                                 cacc[mt][t][1] * cacc[mt][t][1]);
                float m1 = FSQRT(cacc[mt][t][2] * cacc[mt][t][2] +
                                 cacc[mt][t][3] * cacc[mt][t][3]);
                unsigned u0 = __float_as_uint(m0), u1 = __float_as_uint(m1);
                unsigned pk = ((u0 + 0x8000u) >> 16) | ((u1 + 0x8000u) & 0xFFFF0000u);
                mag_lds[wave][t * 16 + n][4 * mt + q] = pk;
            }
        // (no explicit barrier: wave-private LDS; compiler orders via lgkmcnt)

        // mix: y[o][px] += w1[o][so] * mag[so][px]
#pragma unroll
        for (int t = 0; t < 2; ++t) {
            ux4 raw = *(const ux4*)&mag_lds[wave][t * 16 + n][q * 4];
            bfx8 mb = __builtin_bit_cast(bfx8, raw);
#pragma unroll
            for (int mt = 0; mt < 2; ++mt)
                yacc[mt][t] = __builtin_amdgcn_mfma_f32_16x16x32_bf16(
                    wf[mt], mb, yacc[mt][t], 0, 0, 0);
        }
    }

    // epilogue: y-partial for this c-half, fp32, [half][b][o][h][w]
    float* yp = ypart + (size_t)(half * 4 + b) * (32 * 16384) + h * 128;
#pragma unroll
    for (int mt = 0; mt < 2; ++mt)
#pragma unroll
        for (int t = 0; t < 2; ++t) {
            const int w0 = px0 + t * 16 + n;
#pragma unroll
            for (int r = 0; r < 4; ++r)
                yp[(size_t)(mt * 16 + 4 * q + r) * 16384 + w0] = yacc[mt][t][r];
        }
}

// ---- stats: sum / sumsq per (b,o) ----------------------------------------
__global__ void istats(const float* __restrict__ ypart, float* __restrict__ stats)
{
    const int bo = blockIdx.x >> 3, chunk = blockIdx.x & 7;
    const float* y0 = ypart + (size_t)bo * 16384 + chunk * 2048;
    const float* y1 = y0 + YP_HALF;
    float s = 0.f, sq = 0.f;
#pragma unroll
    for (int j = 0; j < 8; ++j) {
        int i = threadIdx.x + j * 256;
        float v = y0[i] + y1[i];
        s += v; sq += v * v;
    }
    for (int off = 32; off > 0; off >>= 1) {
        s  += __shfl_down(s, off);
        sq += __shfl_down(sq, off);
    }
    __shared__ float rs[4][2];
    const int lane = threadIdx.x & 63, wave = threadIdx.x >> 6;
    if (lane == 0) { rs[wave][0] = s; rs[wave][1] = sq; }
    __syncthreads();
    if (threadIdx.x == 0) {
        float S = rs[0][0] + rs[1][0] + rs[2][0] + rs[3][0];
        float Q = rs[0][1] + rs[1][1] + rs[2][1] + rs[3][1];
        atomicAdd(&stats[bo * 2], S);
        atomicAdd(&stats[bo * 2 + 1], Q);
    }
}

// ---- normalize + transposed store via LDS tiles --------------------------
__global__ void inorm2(const float* __restrict__ ypart, const float* __restrict__ stats,
                       float* __restrict__ out)
{
    const int bid = blockIdx.x;                 // 2048 = 128 (b,o) x 16 tiles
    const int bo = bid >> 4, tile = bid & 15;
    const int h0 = (tile >> 2) * 32, w0 = (tile & 3) * 32;
    const float mean = stats[bo * 2] * (1.f / 16384.f);
    float var = stats[bo * 2 + 1] * (1.f / 16384.f) - mean * mean;
    const float rstd = rsqrtf(fmaxf(var, 0.f) + 1e-5f);

    const float* y0 = ypart + (size_t)bo * 16384;
    const float* y1 = y0 + YP_HALF;
    __shared__ float tilebuf[32][33];
    const int r = threadIdx.x >> 3, c4 = (threadIdx.x & 7) * 4;

    const size_t base = (size_t)(h0 + r) * 128 + w0 + c4;
    fx4 a = *(const fx4*)(y0 + base);
    fx4 bb = *(const fx4*)(y1 + base);
#pragma unroll
    for (int j = 0; j < 4; ++j)
        tilebuf[r][c4 + j] = (a[j] + bb[j] - mean) * rstd;
    __syncthreads();
    // out[bo][w0+r][h0+c4+j] = z[h0+c4+j][w0+r]
    float* ob = out + (size_t)bo * 16384 + (size_t)(w0 + r) * 128 + h0 + c4;
    fx4 o4;
#pragma unroll
    for (int j = 0; j < 4; ++j) o4[j] = tilebuf[c4 + j][r];
    *(fx4*)ob = o4;
}

extern "C" void kernel_launch(void* const* d_in, const int* in_sizes, int n_in,
                              void* d_out, int out_size, void* d_ws, size_t ws_size,
                              hipStream_t stream)
{
    const float* x    = (const float*)d_in[0];
    const float* filt = (const float*)d_in[1];
    const float* w1   = (const float*)d_in[2];
    // d_in[3] = b1: cancels under instance norm, unused.
    float* out = (float*)d_out;
    char* ws = (char*)d_ws;

    unsigned*       xrep  = (unsigned*)ws;
    unsigned short* Aw    = (unsigned short*)(ws + A_OFF);
    unsigned short* w1b   = (unsigned short*)(ws + W1B_OFF);
    float*          yp    = (float*)(ws + YP_OFF);
    float*          stats = (float*)(ws + ST_OFF);

    prep_x<<<2048, 256, 0, stream>>>(x, xrep);
    prep_small<<<178, 256, 0, stream>>>(filt, w1, Aw, w1b, stats);
    conv_mix<<<1024, 256, 0, stream>>>((const unsigned short*)xrep, Aw, w1b, yp);
    istats<<<1024, 256, 0, stream>>>(yp, stats);
    inorm2<<<2048, 256, 0, stream>>>(yp, stats, out);
}

// Round 3
// 224.963 us; speedup vs baseline: 1.1061x; 1.0020x over previous
//
#include <hip/hip_runtime.h>

// ---------------------------------------------------------------------------
// EnhancedBlockGabor on MI355X (gfx950)
//   prep       : x -> 4 column-phase-shifted padded bf16 replicas; filters ->
//                A bf16 [48][256]; w1 -> bf16 [32][32][32]; zero stats
//   conv_mix   : implicit-GEMM depthwise conv (mfma 16x16x32 bf16) + |.| +
//                fused channel-mix GEMM; fp32 y-partials (2 c-halves)
//   istats     : sum/sumsq per (b,o) via block reduce + atomics
//   inorm2     : normalize + H<->W transpose via 32x32 LDS tiles
// b1 ignored: per-channel constant cancels under instance norm.
// R3 change: A fragments pinned in VGPRs via empty asm "+v" (R2 showed
// VGPR_Count=80 -> compiler was re-loading 768B/lane of A from L1 every
// channel iteration; that redundant A traffic was ~2/3 of runtime).
// ---------------------------------------------------------------------------

typedef __attribute__((ext_vector_type(8))) short bfx8;
typedef __attribute__((ext_vector_type(4))) short bfx4;
typedef __attribute__((ext_vector_type(4))) float fx4;
typedef __attribute__((ext_vector_type(4))) unsigned ux4;

#define NREP   4
#define RPITCH 144
#define RROWS  144
#define IMG_SH (RROWS * RPITCH)        // 20736 shorts per padded image
#define REP_SH (128 * IMG_SH)          // shorts per replica (all 128 images)
#define XREP_SH (NREP * REP_SH)        // 10,616,832 shorts

#define A_OFF    ((size_t)XREP_SH * 2)             // bytes into ws
#define W1B_OFF  (A_OFF + (size_t)48 * 256 * 2)
#define YP_OFF   (W1B_OFF + (size_t)32 * 32 * 32 * 2)
#define YP_HALF  (4 * 32 * 16384)                  // floats per c-half partial
#define ST_OFF   (YP_OFF + (size_t)2 * YP_HALF * 4)
// total ws need: ST_OFF + 128*2*4 B  (~36.3 MiB)

__device__ __forceinline__ unsigned short f2bf(float f) {
    unsigned u = __float_as_uint(f);
    u = (u + 0x7FFFu + ((u >> 16) & 1u)) >> 16;   // RTNE
    return (unsigned short)u;
}

// ---- merged prep: replicas + A + w1b + stats-zero ------------------------
__global__ void prep(const float* __restrict__ x, const float* __restrict__ filt,
                     const float* __restrict__ w1, unsigned* __restrict__ xrep,
                     unsigned short* __restrict__ A, unsigned short* __restrict__ w1b,
                     float* __restrict__ stats)
{
    const int bid = blockIdx.x;
    if (bid < 2048) {
        const int DW_PER_ROW = RPITCH / 2;             // 72
        const int DW_PER_IMG = IMG_SH / 2;             // 10368
        const int DW_PER_REP = REP_SH / 2;             // 1,327,104
        const int total = NREP * DW_PER_REP;
        for (int i = bid * 256 + threadIdx.x; i < total; i += 2048 * 256) {
            int phi  = i / DW_PER_REP;
            int rem  = i - phi * DW_PER_REP;
            int img  = rem / DW_PER_IMG;
            int rem2 = rem - img * DW_PER_IMG;
            int r    = rem2 / DW_PER_ROW;
            int pd   = rem2 - r * DW_PER_ROW;
            int c0   = 2 * pd + phi;                   // padded col of lo short
            float v0 = 0.f, v1 = 0.f;
            int rr = r - 7;
            if (rr >= 0 && rr < 128) {
                const float* row = x + ((size_t)img * 128 + rr) * 128;
                int cc0 = c0 - 7;
                if (cc0 >= 0 && cc0 < 128) v0 = row[cc0];
                int cc1 = c0 - 6;
                if (cc1 >= 0 && cc1 < 128) v1 = row[cc1];
            }
            xrep[i] = (unsigned)f2bf(v0) | ((unsigned)f2bf(v1) << 16);
        }
    } else {
        int t = (bid - 2048) * 256 + threadIdx.x;
        if (t < 48 * 256) {
            int f = t >> 8, k = t & 255;
            int ky = k >> 4, kx = k & 15;
            float v = 0.f;
            if (ky < 15 && kx < 15) v = filt[(f * 15 + ky) * 15 + kx];
            A[t] = f2bf(v);
        } else if (t < 48 * 256 + 32 * 32 * 32) {
            int j = t - 48 * 256;
            int c = j >> 10, o = (j >> 5) & 31, so = j & 31;
            float v = (so < 24) ? w1[o * 768 + c * 24 + so] : 0.f;
            w1b[j] = f2bf(v);
        } else if (t < 48 * 256 + 32 * 32 * 32 + 256) {
            stats[t - (48 * 256 + 32 * 32 * 32)] = 0.f;
        }
    }
}

// ---- fused conv + magnitude + channel-mix --------------------------------
// grid 1024, XCD-swizzled: each XCD owns one (b,c-half) -> 2.65 MB L2 set.
// WG = 256 thr = 4 waves, one output row h; 16 channels looped.
// A fragments (48x256 filters) PINNED in 96 VGPRs via asm "+v".
__launch_bounds__(256, 2)
__global__ void conv_mix(const unsigned short* __restrict__ xrep,
                         const unsigned short* __restrict__ Aw,
                         const unsigned short* __restrict__ w1b,
                         float* __restrict__ ypart)
{
    __shared__ unsigned mag_lds[4][32][20];        // [wave][px][so-dword pad20]
    const int tid  = threadIdx.x;
    const int lane = tid & 63;
    const int wave = tid >> 6;
    const int n    = lane & 15;                    // MFMA row(A) / col(B,D)
    const int q    = lane >> 4;                    // MFMA k-octet / D row group

    const int bid  = blockIdx.x;
    const int swiz = (bid & 7) * 128 + (bid >> 3); // XCD k -> (b,half)=k, all h
    const int b    = swiz >> 8;
    const int half = (swiz >> 7) & 1;
    const int h    = swiz & 127;

    // zero so=24..31 pads once (dwords 12..15 of each px row)
    if (lane < 32) {
        ux4 z4 = {0u, 0u, 0u, 0u};
        *(ux4*)&mag_lds[wave][lane][12] = z4;
    }

    // A fragments loaded once, then pinned: asm makes them opaque register
    // values the allocator cannot re-materialize from memory.
    ux4 afr[3][8];
#pragma unroll
    for (int mt = 0; mt < 3; ++mt)
#pragma unroll
        for (int s = 0; s < 8; ++s)
            afr[mt][s] = *(const ux4*)(Aw + ((mt * 16 + n) * 256 + s * 32 + q * 8));
#pragma unroll
    for (int mt = 0; mt < 3; ++mt)
#pragma unroll
        for (int s = 0; s < 8; ++s)
            asm volatile("" : "+v"(afr[mt][s]));

    const int px0   = wave * 32;
    const int phi   = n & 3;                           // replica phase
    const int pbase = px0 + (n & 12) + 8 * (q & 1);    // 8B-aligned col start
    const int rbase = h + (q >> 1);                    // + 2s per k-step
    const unsigned short* xb =
        xrep + ((size_t)(phi * 128 + b * 32 + half * 16) * RROWS + rbase) * RPITCH + pbase;

    const fx4 zero4 = {0.f, 0.f, 0.f, 0.f};
    fx4 yacc[2][2];
#pragma unroll
    for (int mt = 0; mt < 2; ++mt)
#pragma unroll
        for (int t = 0; t < 2; ++t) yacc[mt][t] = zero4;

    for (int c = 0; c < 16; ++c) {
        const unsigned short* xc = xb + c * IMG_SH;
        // stage all B data for this channel: 32 aligned 8B loads
        bfx4 braw[2][8][2];
#pragma unroll
        for (int s = 0; s < 8; ++s)
#pragma unroll
            for (int t = 0; t < 2; ++t) {
                const bfx4* p = (const bfx4*)(xc + s * (2 * RPITCH) + t * 16);
                braw[t][s][0] = p[0];
                braw[t][s][1] = p[1];
            }
        const int ch = half * 16 + c;
        bfx8 wf[2];
#pragma unroll
        for (int mt = 0; mt < 2; ++mt)
            wf[mt] = *(const bfx8*)(w1b + ((ch * 32 + mt * 16 + n) * 32 + q * 8));

        fx4 cacc[3][2];
#pragma unroll
        for (int mt = 0; mt < 3; ++mt)
#pragma unroll
            for (int t = 0; t < 2; ++t) cacc[mt][t] = zero4;

#pragma unroll
        for (int s = 0; s < 8; ++s) {
#pragma unroll
            for (int t = 0; t < 2; ++t) {
                bfx8 bf = __builtin_shufflevector(braw[t][s][0], braw[t][s][1],
                                                  0, 1, 2, 3, 4, 5, 6, 7);
#pragma unroll
                for (int mt = 0; mt < 3; ++mt)
                    cacc[mt][t] = __builtin_amdgcn_mfma_f32_16x16x32_bf16(
                        __builtin_bit_cast(bfx8, afr[mt][s]), bf, cacc[mt][t], 0, 0, 0);
            }
        }

        // magnitudes -> wave-private LDS (D rows 4q..4q+3 = two re/im pairs)
#pragma unroll
        for (int t = 0; t < 2; ++t)
#pragma unroll
            for (int mt = 0; mt < 3; ++mt) {
                float m0 = sqrtf(cacc[mt][t][0] * cacc[mt][t][0] +
                                 cacc[mt][t][1] * cacc[mt][t][1]);
                float m1 = sqrtf(cacc[mt][t][2] * cacc[mt][t][2] +
                                 cacc[mt][t][3] * cacc[mt][t][3]);
                unsigned u0 = __float_as_uint(m0), u1 = __float_as_uint(m1);
                unsigned pk = ((u0 + 0x8000u) >> 16) | ((u1 + 0x8000u) & 0xFFFF0000u);
                mag_lds[wave][t * 16 + n][4 * mt + q] = pk;
            }

        // mix: y[o][px] += w1[o][so] * mag[so][px]
#pragma unroll
        for (int t = 0; t < 2; ++t) {
            ux4 raw = *(const ux4*)&mag_lds[wave][t * 16 + n][q * 4];
            bfx8 mb = __builtin_bit_cast(bfx8, raw);
#pragma unroll
            for (int mt = 0; mt < 2; ++mt)
                yacc[mt][t] = __builtin_amdgcn_mfma_f32_16x16x32_bf16(
                    wf[mt], mb, yacc[mt][t], 0, 0, 0);
        }
    }

    // epilogue: y-partial for this c-half, fp32, [half][b][o][h][w]
    float* yp = ypart + (size_t)(half * 4 + b) * (32 * 16384) + h * 128;
#pragma unroll
    for (int mt = 0; mt < 2; ++mt)
#pragma unroll
        for (int t = 0; t < 2; ++t) {
            const int w0 = px0 + t * 16 + n;
#pragma unroll
            for (int r = 0; r < 4; ++r)
                yp[(size_t)(mt * 16 + 4 * q + r) * 16384 + w0] = yacc[mt][t][r];
        }
}

// ---- stats: sum / sumsq per (b,o) ----------------------------------------
__global__ void istats(const float* __restrict__ ypart, float* __restrict__ stats)
{
    const int bo = blockIdx.x >> 3, chunk = blockIdx.x & 7;
    const float* y0 = ypart + (size_t)bo * 16384 + chunk * 2048;
    const float* y1 = y0 + YP_HALF;
    float s = 0.f, sq = 0.f;
#pragma unroll
    for (int j = 0; j < 8; ++j) {
        int i = threadIdx.x + j * 256;
        float v = y0[i] + y1[i];
        s += v; sq += v * v;
    }
    for (int off = 32; off > 0; off >>= 1) {
        s  += __shfl_down(s, off);
        sq += __shfl_down(sq, off);
    }
    __shared__ float rs[4][2];
    const int lane = threadIdx.x & 63, wave = threadIdx.x >> 6;
    if (lane == 0) { rs[wave][0] = s; rs[wave][1] = sq; }
    __syncthreads();
    if (threadIdx.x == 0) {
        float S = rs[0][0] + rs[1][0] + rs[2][0] + rs[3][0];
        float Q = rs[0][1] + rs[1][1] + rs[2][1] + rs[3][1];
        atomicAdd(&stats[bo * 2], S);
        atomicAdd(&stats[bo * 2 + 1], Q);
    }
}

// ---- normalize + transposed store via LDS tiles --------------------------
__global__ void inorm2(const float* __restrict__ ypart, const float* __restrict__ stats,
                       float* __restrict__ out)
{
    const int bid = blockIdx.x;                 // 2048 = 128 (b,o) x 16 tiles
    const int bo = bid >> 4, tile = bid & 15;
    const int h0 = (tile >> 2) * 32, w0 = (tile & 3) * 32;
    const float mean = stats[bo * 2] * (1.f / 16384.f);
    float var = stats[bo * 2 + 1] * (1.f / 16384.f) - mean * mean;
    const float rstd = rsqrtf(fmaxf(var, 0.f) + 1e-5f);

    const float* y0 = ypart + (size_t)bo * 16384;
    const float* y1 = y0 + YP_HALF;
    __shared__ float tilebuf[32][33];
    const int r = threadIdx.x >> 3, c4 = (threadIdx.x & 7) * 4;

    const size_t base = (size_t)(h0 + r) * 128 + w0 + c4;
    fx4 a = *(const fx4*)(y0 + base);
    fx4 bb = *(const fx4*)(y1 + base);
#pragma unroll
    for (int j = 0; j < 4; ++j)
        tilebuf[r][c4 + j] = (a[j] + bb[j] - mean) * rstd;
    __syncthreads();
    // out[bo][w0+r][h0+c4+j] = z[h0+c4+j][w0+r]
    float* ob = out + (size_t)bo * 16384 + (size_t)(w0 + r) * 128 + h0 + c4;
    fx4 o4;
#pragma unroll
    for (int j = 0; j < 4; ++j) o4[j] = tilebuf[c4 + j][r];
    *(fx4*)ob = o4;
}

extern "C" void kernel_launch(void* const* d_in, const int* in_sizes, int n_in,
                              void* d_out, int out_size, void* d_ws, size_t ws_size,
                              hipStream_t stream)
{
    const float* x    = (const float*)d_in[0];
    const float* filt = (const float*)d_in[1];
    const float* w1   = (const float*)d_in[2];
    // d_in[3] = b1: cancels under instance norm, unused.
    float* out = (float*)d_out;
    char* ws = (char*)d_ws;

    unsigned*       xrep  = (unsigned*)ws;
    unsigned short* Aw    = (unsigned short*)(ws + A_OFF);
    unsigned short* w1b   = (unsigned short*)(ws + W1B_OFF);
    float*          yp    = (float*)(ws + YP_OFF);
    float*          stats = (float*)(ws + ST_OFF);

    prep<<<2048 + 178, 256, 0, stream>>>(x, filt, w1, xrep, Aw, w1b, stats);
    conv_mix<<<1024, 256, 0, stream>>>((const unsigned short*)xrep, Aw, w1b, yp);
    istats<<<1024, 256, 0, stream>>>(yp, stats);
    inorm2<<<2048, 256, 0, stream>>>(yp, stats, out);
}

// Round 4
// 219.919 us; speedup vs baseline: 1.1315x; 1.0229x over previous
//
#include <hip/hip_runtime.h>

// ---------------------------------------------------------------------------
// EnhancedBlockGabor on MI355X (gfx950)
//   prep       : x -> 4 column-phase-shifted padded bf16 replicas; filters ->
//                A bf16 [48][256]; w1 -> bf16 [32][32][32]; zero stats
//   conv_mix   : implicit-GEMM depthwise conv (mfma 16x16x32 bf16) + |.| +
//                fused channel-mix GEMM; fp32 y-partials (2 c-halves)
//   istats     : sum/sumsq per (b,o) via block reduce + atomics
//   inorm2     : normalize + H<->W transpose via 32x32 LDS tiles
// b1 ignored: per-channel constant cancels under instance norm.
// R4 change: amdgpu_waves_per_eu(2,2) pins the allocator at a 256-reg budget
// (R2/R3 showed it squeezing to 88 arch VGPRs chasing 5 waves/EU, which
// serialized the 32 B-loads per channel into ~16 load->wait->use round trips);
// B staging is batch-issued and register-pinned so each c-iter has ONE wait.
// ---------------------------------------------------------------------------

typedef __attribute__((ext_vector_type(8))) short bfx8;
typedef __attribute__((ext_vector_type(4))) short bfx4;
typedef __attribute__((ext_vector_type(4))) float fx4;
typedef __attribute__((ext_vector_type(4))) unsigned ux4;
typedef __attribute__((ext_vector_type(2))) unsigned ux2;

#define NREP   4
#define RPITCH 144
#define RROWS  144
#define IMG_SH (RROWS * RPITCH)        // 20736 shorts per padded image
#define REP_SH (128 * IMG_SH)          // shorts per replica (all 128 images)
#define XREP_SH (NREP * REP_SH)        // 10,616,832 shorts

#define A_OFF    ((size_t)XREP_SH * 2)             // bytes into ws
#define W1B_OFF  (A_OFF + (size_t)48 * 256 * 2)
#define YP_OFF   (W1B_OFF + (size_t)32 * 32 * 32 * 2)
#define YP_HALF  (4 * 32 * 16384)                  // floats per c-half partial
#define ST_OFF   (YP_OFF + (size_t)2 * YP_HALF * 4)
// total ws need: ST_OFF + 128*2*4 B  (~36.3 MiB)

__device__ __forceinline__ unsigned short f2bf(float f) {
    unsigned u = __float_as_uint(f);
    u = (u + 0x7FFFu + ((u >> 16) & 1u)) >> 16;   // RTNE
    return (unsigned short)u;
}

// ---- merged prep: replicas + A + w1b + stats-zero ------------------------
__global__ void prep(const float* __restrict__ x, const float* __restrict__ filt,
                     const float* __restrict__ w1, unsigned* __restrict__ xrep,
                     unsigned short* __restrict__ A, unsigned short* __restrict__ w1b,
                     float* __restrict__ stats)
{
    const int bid = blockIdx.x;
    if (bid < 2048) {
        const int DW_PER_ROW = RPITCH / 2;             // 72
        const int DW_PER_IMG = IMG_SH / 2;             // 10368
        const int DW_PER_REP = REP_SH / 2;             // 1,327,104
        const int total = NREP * DW_PER_REP;
        for (int i = bid * 256 + threadIdx.x; i < total; i += 2048 * 256) {
            int phi  = i / DW_PER_REP;
            int rem  = i - phi * DW_PER_REP;
            int img  = rem / DW_PER_IMG;
            int rem2 = rem - img * DW_PER_IMG;
            int r    = rem2 / DW_PER_ROW;
            int pd   = rem2 - r * DW_PER_ROW;
            int c0   = 2 * pd + phi;                   // padded col of lo short
            float v0 = 0.f, v1 = 0.f;
            int rr = r - 7;
            if (rr >= 0 && rr < 128) {
                const float* row = x + ((size_t)img * 128 + rr) * 128;
                int cc0 = c0 - 7;
                if (cc0 >= 0 && cc0 < 128) v0 = row[cc0];
                int cc1 = c0 - 6;
                if (cc1 >= 0 && cc1 < 128) v1 = row[cc1];
            }
            xrep[i] = (unsigned)f2bf(v0) | ((unsigned)f2bf(v1) << 16);
        }
    } else {
        int t = (bid - 2048) * 256 + threadIdx.x;
        if (t < 48 * 256) {
            int f = t >> 8, k = t & 255;
            int ky = k >> 4, kx = k & 15;
            float v = 0.f;
            if (ky < 15 && kx < 15) v = filt[(f * 15 + ky) * 15 + kx];
            A[t] = f2bf(v);
        } else if (t < 48 * 256 + 32 * 32 * 32) {
            int j = t - 48 * 256;
            int c = j >> 10, o = (j >> 5) & 31, so = j & 31;
            float v = (so < 24) ? w1[o * 768 + c * 24 + so] : 0.f;
            w1b[j] = f2bf(v);
        } else if (t < 48 * 256 + 32 * 32 * 32 + 256) {
            stats[t - (48 * 256 + 32 * 32 * 32)] = 0.f;
        }
    }
}

// ---- fused conv + magnitude + channel-mix --------------------------------
// grid 1024, XCD-swizzled: each XCD owns one (b,c-half) -> 2.65 MB L2 set.
// WG = 256 thr = 4 waves, one output row h; 16 channels looped.
// waves_per_eu(2,2): hard 256-reg budget, 2 blocks/CU, 2 clean grid passes.
__global__ void __attribute__((amdgpu_waves_per_eu(2, 2)))
__launch_bounds__(256)
conv_mix(const unsigned short* __restrict__ xrep,
         const unsigned short* __restrict__ Aw,
         const unsigned short* __restrict__ w1b,
         float* __restrict__ ypart)
{
    __shared__ unsigned mag_lds[4][32][20];        // [wave][px][so-dword pad20]
    const int tid  = threadIdx.x;
    const int lane = tid & 63;
    const int wave = tid >> 6;
    const int n    = lane & 15;                    // MFMA row(A) / col(B,D)
    const int q    = lane >> 4;                    // MFMA k-octet / D row group

    const int bid  = blockIdx.x;
    const int swiz = (bid & 7) * 128 + (bid >> 3); // XCD k -> (b,half)=k, all h
    const int b    = swiz >> 8;
    const int half = (swiz >> 7) & 1;
    const int h    = swiz & 127;

    // zero so=24..31 pads once (dwords 12..15 of each px row)
    if (lane < 32) {
        ux4 z4 = {0u, 0u, 0u, 0u};
        *(ux4*)&mag_lds[wave][lane][12] = z4;
    }

    // A fragments loaded once, pinned (R3 evidence: they land in AGPRs,
    // MFMA reads A from AGPR directly on gfx950 -- free).
    ux4 afr[3][8];
#pragma unroll
    for (int mt = 0; mt < 3; ++mt)
#pragma unroll
        for (int s = 0; s < 8; ++s)
            afr[mt][s] = *(const ux4*)(Aw + ((mt * 16 + n) * 256 + s * 32 + q * 8));
#pragma unroll
    for (int mt = 0; mt < 3; ++mt)
#pragma unroll
        for (int s = 0; s < 8; ++s)
            asm volatile("" : "+v"(afr[mt][s]));

    const int px0   = wave * 32;
    const int phi   = n & 3;                           // replica phase
    const int pbase = px0 + (n & 12) + 8 * (q & 1);    // 8B-aligned col start
    const int rbase = h + (q >> 1);                    // + 2s per k-step
    const unsigned short* xb =
        xrep + ((size_t)(phi * 128 + b * 32 + half * 16) * RROWS + rbase) * RPITCH + pbase;

    const fx4 zero4 = {0.f, 0.f, 0.f, 0.f};
    fx4 yacc[2][2];
#pragma unroll
    for (int mt = 0; mt < 2; ++mt)
#pragma unroll
        for (int t = 0; t < 2; ++t) yacc[mt][t] = zero4;

    for (int c = 0; c < 16; ++c) {
        const unsigned short* xc = xb + c * IMG_SH;
        const int ch = half * 16 + c;
        // w1 fragments issued first so their latency hides under B batch
        bfx8 wf[2];
#pragma unroll
        for (int mt = 0; mt < 2; ++mt)
            wf[mt] = *(const bfx8*)(w1b + ((ch * 32 + mt * 16 + n) * 32 + q * 8));

        // stage ALL B data for this channel: 32 aligned 8B loads, batch
        // issued, then pinned -> one vmcnt wait point for the whole batch.
        ux2 braw[2][8][2];
#pragma unroll
        for (int s = 0; s < 8; ++s)
#pragma unroll
            for (int t = 0; t < 2; ++t) {
                const ux2* p = (const ux2*)(xc + s * (2 * RPITCH) + t * 16);
                braw[t][s][0] = p[0];
                braw[t][s][1] = p[1];
            }
#pragma unroll
        for (int s = 0; s < 8; ++s)
#pragma unroll
            for (int t = 0; t < 2; ++t) {
                asm volatile("" : "+v"(braw[t][s][0]));
                asm volatile("" : "+v"(braw[t][s][1]));
            }

        fx4 cacc[3][2];
#pragma unroll
        for (int mt = 0; mt < 3; ++mt)
#pragma unroll
            for (int t = 0; t < 2; ++t) cacc[mt][t] = zero4;

#pragma unroll
        for (int s = 0; s < 8; ++s) {
#pragma unroll
            for (int t = 0; t < 2; ++t) {
                ux4 bu = {braw[t][s][0][0], braw[t][s][0][1],
                          braw[t][s][1][0], braw[t][s][1][1]};
                bfx8 bf = __builtin_bit_cast(bfx8, bu);
#pragma unroll
                for (int mt = 0; mt < 3; ++mt)
                    cacc[mt][t] = __builtin_amdgcn_mfma_f32_16x16x32_bf16(
                        __builtin_bit_cast(bfx8, afr[mt][s]), bf, cacc[mt][t], 0, 0, 0);
            }
        }

        // magnitudes -> wave-private LDS (D rows 4q..4q+3 = two re/im pairs)
#pragma unroll
        for (int t = 0; t < 2; ++t)
#pragma unroll
            for (int mt = 0; mt < 3; ++mt) {
                float m0 = sqrtf(cacc[mt][t][0] * cacc[mt][t][0] +
                                 cacc[mt][t][1] * cacc[mt][t][1]);
                float m1 = sqrtf(cacc[mt][t][2] * cacc[mt][t][2] +
                                 cacc[mt][t][3] * cacc[mt][t][3]);
                unsigned u0 = __float_as_uint(m0), u1 = __float_as_uint(m1);
                unsigned pk = ((u0 + 0x8000u) >> 16) | ((u1 + 0x8000u) & 0xFFFF0000u);
                mag_lds[wave][t * 16 + n][4 * mt + q] = pk;
            }

        // mix: y[o][px] += w1[o][so] * mag[so][px]
#pragma unroll
        for (int t = 0; t < 2; ++t) {
            ux4 raw = *(const ux4*)&mag_lds[wave][t * 16 + n][q * 4];
            bfx8 mb = __builtin_bit_cast(bfx8, raw);
#pragma unroll
            for (int mt = 0; mt < 2; ++mt)
                yacc[mt][t] = __builtin_amdgcn_mfma_f32_16x16x32_bf16(
                    wf[mt], mb, yacc[mt][t], 0, 0, 0);
        }
    }

    // epilogue: y-partial for this c-half, fp32, [half][b][o][h][w]
    float* yp = ypart + (size_t)(half * 4 + b) * (32 * 16384) + h * 128;
#pragma unroll
    for (int mt = 0; mt < 2; ++mt)
#pragma unroll
        for (int t = 0; t < 2; ++t) {
            const int w0 = px0 + t * 16 + n;
#pragma unroll
            for (int r = 0; r < 4; ++r)
                yp[(size_t)(mt * 16 + 4 * q + r) * 16384 + w0] = yacc[mt][t][r];
        }
}

// ---- stats: sum / sumsq per (b,o) ----------------------------------------
__global__ void istats(const float* __restrict__ ypart, float* __restrict__ stats)
{
    const int bo = blockIdx.x >> 3, chunk = blockIdx.x & 7;
    const float* y0 = ypart + (size_t)bo * 16384 + chunk * 2048;
    const float* y1 = y0 + YP_HALF;
    float s = 0.f, sq = 0.f;
#pragma unroll
    for (int j = 0; j < 8; ++j) {
        int i = threadIdx.x + j * 256;
        float v = y0[i] + y1[i];
        s += v; sq += v * v;
    }
    for (int off = 32; off > 0; off >>= 1) {
        s  += __shfl_down(s, off);
        sq += __shfl_down(sq, off);
    }
    __shared__ float rs[4][2];
    const int lane = threadIdx.x & 63, wave = threadIdx.x >> 6;
    if (lane == 0) { rs[wave][0] = s; rs[wave][1] = sq; }
    __syncthreads();
    if (threadIdx.x == 0) {
        float S = rs[0][0] + rs[1][0] + rs[2][0] + rs[3][0];
        float Q = rs[0][1] + rs[1][1] + rs[2][1] + rs[3][1];
        atomicAdd(&stats[bo * 2], S);
        atomicAdd(&stats[bo * 2 + 1], Q);
    }
}

// ---- normalize + transposed store via LDS tiles --------------------------
__global__ void inorm2(const float* __restrict__ ypart, const float* __restrict__ stats,
                       float* __restrict__ out)
{
    const int bid = blockIdx.x;                 // 2048 = 128 (b,o) x 16 tiles
    const int bo = bid >> 4, tile = bid & 15;
    const int h0 = (tile >> 2) * 32, w0 = (tile & 3) * 32;
    const float mean = stats[bo * 2] * (1.f / 16384.f);
    float var = stats[bo * 2 + 1] * (1.f / 16384.f) - mean * mean;
    const float rstd = rsqrtf(fmaxf(var, 0.f) + 1e-5f);

    const float* y0 = ypart + (size_t)bo * 16384;
    const float* y1 = y0 + YP_HALF;
    __shared__ float tilebuf[32][33];
    const int r = threadIdx.x >> 3, c4 = (threadIdx.x & 7) * 4;

    const size_t base = (size_t)(h0 + r) * 128 + w0 + c4;
    fx4 a = *(const fx4*)(y0 + base);
    fx4 bb = *(const fx4*)(y1 + base);
#pragma unroll
    for (int j = 0; j < 4; ++j)
        tilebuf[r][c4 + j] = (a[j] + bb[j] - mean) * rstd;
    __syncthreads();
    // out[bo][w0+r][h0+c4+j] = z[h0+c4+j][w0+r]
    float* ob = out + (size_t)bo * 16384 + (size_t)(w0 + r) * 128 + h0 + c4;
    fx4 o4;
#pragma unroll
    for (int j = 0; j < 4; ++j) o4[j] = tilebuf[c4 + j][r];
    *(fx4*)ob = o4;
}

extern "C" void kernel_launch(void* const* d_in, const int* in_sizes, int n_in,
                              void* d_out, int out_size, void* d_ws, size_t ws_size,
                              hipStream_t stream)
{
    const float* x    = (const float*)d_in[0];
    const float* filt = (const float*)d_in[1];
    const float* w1   = (const float*)d_in[2];
    // d_in[3] = b1: cancels under instance norm, unused.
    float* out = (float*)d_out;
    char* ws = (char*)d_ws;

    unsigned*       xrep  = (unsigned*)ws;
    unsigned short* Aw    = (unsigned short*)(ws + A_OFF);
    unsigned short* w1b   = (unsigned short*)(ws + W1B_OFF);
    float*          yp    = (float*)(ws + YP_OFF);
    float*          stats = (float*)(ws + ST_OFF);

    prep<<<2048 + 178, 256, 0, stream>>>(x, filt, w1, xrep, Aw, w1b, stats);
    conv_mix<<<1024, 256, 0, stream>>>((const unsigned short*)xrep, Aw, w1b, yp);
    istats<<<1024, 256, 0, stream>>>(yp, stats);
    inorm2<<<2048, 256, 0, stream>>>(yp, stats, out);
}

// Round 5
// 138.953 us; speedup vs baseline: 1.7908x; 1.5827x over previous
//
#include <hip/hip_runtime.h>

// ---------------------------------------------------------------------------
// EnhancedBlockGabor on MI355X (gfx950)
//   prep     : x -> 2 column-phase-shifted padded bf16 replicas; filters ->
//              A bf16 [48][256]; w1 -> bf16 [32][32][32]; zero stats
//   conv_mix : per (b,h) block, 32 channels; per channel stage 16 rows x 2
//              phase replicas into LDS (coalesced, double-buffered), gather
//              B-fragments via 4B-aligned ds_read_b32, mfma conv + |.| +
//              mixing GEMM; epilogue: y store + fused instance-norm stats
//   inorm2   : normalize + H<->W transpose via 32x32 LDS tiles
// b1 ignored: per-channel constant cancels under instance norm.
// R5: R1-R4 were L1/TA-bound — every B-load instruction straddled 4 global
// replicas (~650 L2 lines per CU-c-iter through one TCP ≈ 10k cy/c-iter,
// invariant under all register strategies). B now comes from LDS; global
// traffic is coalesced row staging only. istats fused; prep halved.
// ---------------------------------------------------------------------------

typedef __attribute__((ext_vector_type(8))) short bfx8;
typedef __attribute__((ext_vector_type(4))) float fx4;
typedef __attribute__((ext_vector_type(4))) unsigned ux4;

#define NREP   2
#define RPITCH 144
#define RROWS  144
#define IMG_SH (RROWS * RPITCH)            // 20736 shorts per padded image
#define REP_SH (128 * IMG_SH)              // shorts per replica
#define REPBYTES ((size_t)REP_SH * 2)      // 5,308,416 B
#define XREP_SH (NREP * REP_SH)

#define A_OFF    ((size_t)XREP_SH * 2)
#define W1B_OFF  (A_OFF + (size_t)48 * 256 * 2)
#define YP_OFF   (W1B_OFF + (size_t)32 * 32 * 32 * 2)
#define ST_OFF   (YP_OFF + (size_t)128 * 16384 * 4)
// total ws: ~19.3 MiB

// LDS staging geometry: per buffer, 2 replicas x 16 rows x 288 B, replica
// stride 5184 B (1296 dw == 16 mod 32 -> all frag reads exactly 2-way banked)
#define STG_REP_B 5184
#define STG_BUF_B (2 * STG_REP_B)          // 10368 B per buffer

__device__ __forceinline__ unsigned short f2bf(float f) {
    unsigned u = __float_as_uint(f);
    u = (u + 0x7FFFu + ((u >> 16) & 1u)) >> 16;   // RTNE
    return (unsigned short)u;
}

// ---- merged prep: 2 replicas + A + w1b + stats-zero ----------------------
__global__ void prep(const float* __restrict__ x, const float* __restrict__ filt,
                     const float* __restrict__ w1, unsigned* __restrict__ xrep,
                     unsigned short* __restrict__ A, unsigned short* __restrict__ w1b,
                     float* __restrict__ stats)
{
    const int bid = blockIdx.x;
    if (bid < 2048) {
        const int DW_PER_ROW = RPITCH / 2;             // 72
        const int DW_PER_IMG = IMG_SH / 2;             // 10368
        const int DW_PER_REP = REP_SH / 2;             // 1,327,104
        const int total = NREP * DW_PER_REP;
        for (int i = bid * 256 + threadIdx.x; i < total; i += 2048 * 256) {
            int phi  = i / DW_PER_REP;                 // 0 or 1
            int rem  = i - phi * DW_PER_REP;
            int img  = rem / DW_PER_IMG;
            int rem2 = rem - img * DW_PER_IMG;
            int r    = rem2 / DW_PER_ROW;
            int pd   = rem2 - r * DW_PER_ROW;
            int c0   = 2 * pd + phi;                   // padded col of lo short
            float v0 = 0.f, v1 = 0.f;
            int rr = r - 7;
            if (rr >= 0 && rr < 128) {
                const float* row = x + ((size_t)img * 128 + rr) * 128;
                int cc0 = c0 - 7;
                if (cc0 >= 0 && cc0 < 128) v0 = row[cc0];
                int cc1 = c0 - 6;
                if (cc1 >= 0 && cc1 < 128) v1 = row[cc1];
            }
            xrep[i] = (unsigned)f2bf(v0) | ((unsigned)f2bf(v1) << 16);
        }
    } else {
        int t = (bid - 2048) * 256 + threadIdx.x;
        if (t < 48 * 256) {
            int f = t >> 8, k = t & 255;
            int ky = k >> 4, kx = k & 15;
            float v = 0.f;
            if (ky < 15 && kx < 15) v = filt[(f * 15 + ky) * 15 + kx];
            A[t] = f2bf(v);
        } else if (t < 48 * 256 + 32 * 32 * 32) {
            int j = t - 48 * 256;
            int c = j >> 10, o = (j >> 5) & 31, so = j & 31;
            float v = (so < 24) ? w1[o * 768 + c * 24 + so] : 0.f;
            w1b[j] = f2bf(v);
        } else if (t < 48 * 256 + 32 * 32 * 32 + 256) {
            stats[t - (48 * 256 + 32 * 32 * 32)] = 0.f;
        }
    }
}

// ---- fused conv + magnitude + channel-mix + stats ------------------------
// grid 512 = 4 b x 128 h, XCD-swizzled (2 XCDs per image). 2 blocks/CU,
// exactly one pass. Per c-iter: stage 2 reps x 16 rows x 288 B into LDS
// (3 dwordx4 loads/thread, coalesced, double-buffered under compute).
__global__ void __attribute__((amdgpu_waves_per_eu(2, 2)))
__launch_bounds__(256)
conv_mix(const unsigned short* __restrict__ xrep,
         const unsigned short* __restrict__ Aw,
         const unsigned short* __restrict__ w1b,
         float* __restrict__ ypart, float* __restrict__ stats)
{
    __shared__ char stage[2 * STG_BUF_B];          // 20736 B
    __shared__ unsigned mag_lds[4][32][20];        // 10240 B [wave][px][pad20]
    __shared__ float stat_lds[4][4][16];           // 1 KB

    const int tid  = threadIdx.x;
    const int lane = tid & 63;
    const int wave = tid >> 6;
    const int n    = lane & 15;                    // MFMA row(A) / col(B,D)
    const int q    = lane >> 4;                    // MFMA k-octet / D row group

    const int bid = blockIdx.x;                    // xcd = bid & 7
    const int b   = (bid >> 1) & 3;
    const int h   = (bid & 1) * 64 + (bid >> 3);

    if (lane < 32) {                               // zero so=24..31 pads
        ux4 z4 = {0u, 0u, 0u, 0u};
        *(ux4*)&mag_lds[wave][lane][12] = z4;
    }

    // A fragments pinned (land in AGPRs; MFMA reads A from AGPR on gfx950)
    ux4 afr[3][8];
#pragma unroll
    for (int mt = 0; mt < 3; ++mt)
#pragma unroll
        for (int s = 0; s < 8; ++s)
            afr[mt][s] = *(const ux4*)(Aw + ((mt * 16 + n) * 256 + s * 32 + q * 8));
#pragma unroll
    for (int mt = 0; mt < 3; ++mt)
#pragma unroll
        for (int s = 0; s < 8; ++s)
            asm volatile("" : "+v"(afr[mt][s]));

    const int px0 = wave * 32;
    const int p   = n & 1;                         // LDS phase replica
    // frag v-base (bytes within a buffer); + buf*STG_BUF_B per iter
    const int fbase = p * STG_REP_B + (q >> 1) * 288 +
                      (px0 + (n - p) + 8 * (q & 1)) * 2;

    // staging slot addressing (per thread): slots of 16 B; 288 per replica
    const char* gx = (const char*)xrep;
    const int s1p  = (tid + 256) >= 288;           // slot1 replica
    const int off1 = tid + 256 - (s1p ? 288 : 0);
    const size_t ib0 = ((size_t)(b * 32) * RROWS + h) * (RPITCH * 2); // ch 0

    const fx4 zero4 = {0.f, 0.f, 0.f, 0.f};
    fx4 yacc[2][2];
#pragma unroll
    for (int mt = 0; mt < 2; ++mt)
#pragma unroll
        for (int t = 0; t < 2; ++t) yacc[mt][t] = zero4;

    // prologue: stage channel 0 into buf 0
    {
        const char* g = gx + ib0;
        ux4 v0 = *(const ux4*)(g + tid * 16);
        ux4 v1 = *(const ux4*)(g + (size_t)s1p * REPBYTES + off1 * 16);
        ux4 v2 = {0u, 0u, 0u, 0u};
        if (tid < 64) v2 = *(const ux4*)(g + REPBYTES + (tid + 224) * 16);
        *(ux4*)(stage + tid * 16) = v0;
        *(ux4*)(stage + s1p * STG_REP_B + off1 * 16) = v1;
        if (tid < 64) *(ux4*)(stage + STG_REP_B + (tid + 224) * 16) = v2;
    }
    __syncthreads();

    for (int c = 0; c < 32; ++c) {
        // issue staging loads for channel c+1 (land during compute)
        ux4 nv0, nv1, nv2;
        if (c < 31) {
            const char* g = gx + ib0 + (size_t)(c + 1) * (IMG_SH * 2);
            nv0 = *(const ux4*)(g + tid * 16);
            nv1 = *(const ux4*)(g + (size_t)s1p * REPBYTES + off1 * 16);
            if (tid < 64) nv2 = *(const ux4*)(g + REPBYTES + (tid + 224) * 16);
        }

        bfx8 wf[2];
#pragma unroll
        for (int mt = 0; mt < 2; ++mt)
            wf[mt] = *(const bfx8*)(w1b + ((c * 32 + mt * 16 + n) * 32 + q * 8));

        const char* fb = stage + (c & 1) * STG_BUF_B + fbase;

        fx4 cacc[3][2];
#pragma unroll
        for (int mt = 0; mt < 3; ++mt)
#pragma unroll
            for (int t = 0; t < 2; ++t) cacc[mt][t] = zero4;

#pragma unroll
        for (int s = 0; s < 8; ++s) {
#pragma unroll
            for (int t = 0; t < 2; ++t) {
                const char* a = fb + s * 576 + t * 32;
                ux4 bu = {*(const unsigned*)(a),     *(const unsigned*)(a + 4),
                          *(const unsigned*)(a + 8), *(const unsigned*)(a + 12)};
                bfx8 bf = __builtin_bit_cast(bfx8, bu);
#pragma unroll
                for (int mt = 0; mt < 3; ++mt)
                    cacc[mt][t] = __builtin_amdgcn_mfma_f32_16x16x32_bf16(
                        __builtin_bit_cast(bfx8, afr[mt][s]), bf, cacc[mt][t], 0, 0, 0);
            }
        }

        // magnitudes -> wave-private LDS
#pragma unroll
        for (int t = 0; t < 2; ++t)
#pragma unroll
            for (int mt = 0; mt < 3; ++mt) {
                float m0 = sqrtf(cacc[mt][t][0] * cacc[mt][t][0] +
                                 cacc[mt][t][1] * cacc[mt][t][1]);
                float m1 = sqrtf(cacc[mt][t][2] * cacc[mt][t][2] +
                                 cacc[mt][t][3] * cacc[mt][t][3]);
                unsigned u0 = __float_as_uint(m0), u1 = __float_as_uint(m1);
                unsigned pk = ((u0 + 0x8000u) >> 16) | ((u1 + 0x8000u) & 0xFFFF0000u);
                mag_lds[wave][t * 16 + n][4 * mt + q] = pk;
            }

        // mix
#pragma unroll
        for (int t = 0; t < 2; ++t) {
            ux4 raw = *(const ux4*)&mag_lds[wave][t * 16 + n][q * 4];
            bfx8 mb = __builtin_bit_cast(bfx8, raw);
#pragma unroll
            for (int mt = 0; mt < 2; ++mt)
                yacc[mt][t] = __builtin_amdgcn_mfma_f32_16x16x32_bf16(
                    wf[mt], mb, yacc[mt][t], 0, 0, 0);
        }

        // write next channel's staging into the other buffer, then barrier
        if (c < 31) {
            char* lb = stage + ((c + 1) & 1) * STG_BUF_B;
            *(ux4*)(lb + tid * 16) = nv0;
            *(ux4*)(lb + s1p * STG_REP_B + off1 * 16) = nv1;
            if (tid < 64) *(ux4*)(lb + STG_REP_B + (tid + 224) * 16) = nv2;
        }
        __syncthreads();
    }

    // ---- epilogue: y store + fused instance-norm partial stats ----------
    float* yp = ypart + (size_t)(b * 32) * 16384 + h * 128;
#pragma unroll
    for (int mt = 0; mt < 2; ++mt)
#pragma unroll
        for (int t = 0; t < 2; ++t) {
            const int w0 = px0 + t * 16 + n;
#pragma unroll
            for (int r = 0; r < 4; ++r)
                yp[(size_t)(mt * 16 + 4 * q + r) * 16384 + w0] = yacc[mt][t][r];
        }

    float sv[8], qv[8];
#pragma unroll
    for (int mt = 0; mt < 2; ++mt)
#pragma unroll
        for (int r = 0; r < 4; ++r) {
            float v0 = yacc[mt][0][r], v1 = yacc[mt][1][r];
            sv[mt * 4 + r] = v0 + v1;
            qv[mt * 4 + r] = v0 * v0 + v1 * v1;
        }
#pragma unroll
    for (int m = 1; m <= 8; m <<= 1)
#pragma unroll
        for (int i = 0; i < 8; ++i) {
            sv[i] += __shfl_xor(sv[i], m);
            qv[i] += __shfl_xor(qv[i], m);
        }
    if (n == 0) {
#pragma unroll
        for (int i = 0; i < 8; ++i) {
            stat_lds[wave][q][i]     = sv[i];
            stat_lds[wave][q][i + 8] = qv[i];
        }
    }
    __syncthreads();
    if (tid < 64) {
        int qq = tid >> 4, i = tid & 15;
        float acc = stat_lds[0][qq][i] + stat_lds[1][qq][i] +
                    stat_lds[2][qq][i] + stat_lds[3][qq][i];
        int kind = i >> 3, mt = (i >> 2) & 1, r = i & 3;
        int o = mt * 16 + 4 * qq + r;
        atomicAdd(&stats[(b * 32 + o) * 2 + kind], acc);
    }
}

// ---- normalize + transposed store via LDS tiles --------------------------
__global__ void inorm2(const float* __restrict__ ypart, const float* __restrict__ stats,
                       float* __restrict__ out)
{
    const int bid = blockIdx.x;                 // 2048 = 128 (b,o) x 16 tiles
    const int bo = bid >> 4, tile = bid & 15;
    const int h0 = (tile >> 2) * 32, w0 = (tile & 3) * 32;
    const float mean = stats[bo * 2] * (1.f / 16384.f);
    float var = stats[bo * 2 + 1] * (1.f / 16384.f) - mean * mean;
    const float rstd = rsqrtf(fmaxf(var, 0.f) + 1e-5f);

    const float* y0 = ypart + (size_t)bo * 16384;
    __shared__ float tilebuf[32][33];
    const int r = threadIdx.x >> 3, c4 = (threadIdx.x & 7) * 4;

    const size_t base = (size_t)(h0 + r) * 128 + w0 + c4;
    fx4 a = *(const fx4*)(y0 + base);
#pragma unroll
    for (int j = 0; j < 4; ++j)
        tilebuf[r][c4 + j] = (a[j] - mean) * rstd;
    __syncthreads();
    float* ob = out + (size_t)bo * 16384 + (size_t)(w0 + r) * 128 + h0 + c4;
    fx4 o4;
#pragma unroll
    for (int j = 0; j < 4; ++j) o4[j] = tilebuf[c4 + j][r];
    *(fx4*)ob = o4;
}

extern "C" void kernel_launch(void* const* d_in, const int* in_sizes, int n_in,
                              void* d_out, int out_size, void* d_ws, size_t ws_size,
                              hipStream_t stream)
{
    const float* x    = (const float*)d_in[0];
    const float* filt = (const float*)d_in[1];
    const float* w1   = (const float*)d_in[2];
    // d_in[3] = b1: cancels under instance norm, unused.
    float* out = (float*)d_out;
    char* ws = (char*)d_ws;

    unsigned*       xrep  = (unsigned*)ws;
    unsigned short* Aw    = (unsigned short*)(ws + A_OFF);
    unsigned short* w1b   = (unsigned short*)(ws + W1B_OFF);
    float*          yp    = (float*)(ws + YP_OFF);
    float*          stats = (float*)(ws + ST_OFF);

    prep<<<2048 + 178, 256, 0, stream>>>(x, filt, w1, xrep, Aw, w1b, stats);
    conv_mix<<<512, 256, 0, stream>>>((const unsigned short*)xrep, Aw, w1b, yp, stats);
    inorm2<<<2048, 256, 0, stream>>>(yp, stats, out);
}